// Round 4
// baseline (867.270 us; speedup 1.0000x reference)
//
#include <hip/hip_runtime.h>
#include <hip/hip_bf16.h>

// GCN forward: 2-layer GCNConv + log_softmax.
// N=100000, E=3200000, F_IN=2000, H=16, C=3.
//
// Measured model (R1-R3): dur_us ~= fixed ~490us harness d_ws poison fill
// (in timed window, not ours) + our kernels (~340us). This round hides the
// CSR-prep (count/scatter, atomic-bound, low-BW) under the BW-bound GEMM by
// fusing them as heterogeneous blocks of the same launch:
//  K0  zero_k   : cnt+cursor = 0
//  K1  fused_a  : [gemm rows 0..50k  (t1 = x@W1, raw) || count cnt[dst]++]
//  K2  scan_k   : rowptr = exclusive_scan(cnt); dinv = rsqrt(cnt+1) fused
//  K3  fused_b  : [gemm rows 50k..N || scatter -> CSR col]
//  K4  agg1     : h = relu(dinv[i]*(t1[i]*dinv[i] + sum t1[s]*dinv[s]) + b1)
//                 t2s[i] = (h @ W2) * dinv[i]   (16 lanes/node, fused)
//  K5  agg2     : logits = dinv*(t2s[i]+sum t2s[col]) + b2; out = log_softmax
// dinv folded into agg1 (not gemm) so gemm has no dependency on count/scan.

#define FIN   2000
#define HDIM  16
#define KB    40          // K-chunk staged in LDS
#define NCHUNK (FIN / KB) // 50
#define KSTRIDE 65        // padded k-stride (words) of transposed x tile
#define EPB   1024        // edges per light (count/scatter) block

__global__ void zero_k(int4* __restrict__ p, int n4) {
    int i = blockIdx.x * 256 + threadIdx.x;
    if (i < n4) p[i] = make_int4(0, 0, 0, 0);
}

// ---- gemm body: t1[row] = x[row] @ W1 (raw, no dinv) --------------------
// 1 wave, 64 rows. x tile staged in LDS transposed [k][row], k-stride 65.
// Double-buffered register staging (10 float4/lane in flight ~ 10KB/wave).
__device__ __forceinline__ void gemm_body(const float* __restrict__ x,
                                          const float* __restrict__ W1,
                                          float* __restrict__ t1,
                                          float xT[2][KB * KSTRIDE],
                                          long base, int n) {
    const int lane = threadIdx.x;
    float4 st[10];

#define STAGE_LOAD(c)                                                       \
    {                                                                       \
        _Pragma("unroll")                                                   \
        for (int i = 0; i < 10; ++i) {                                      \
            int job = i * 64 + lane;                                        \
            int jr = job / 10, jk = job - jr * 10;                          \
            long gr = base + jr; if (gr >= n) gr = n - 1;                   \
            st[i] = *(const float4*)(x + gr * FIN + (c) * KB + jk * 4);     \
        }                                                                   \
    }
#define STAGE_WRITE(bsel)                                                   \
    {                                                                       \
        float* p = &xT[(bsel)][0];                                          \
        _Pragma("unroll")                                                   \
        for (int i = 0; i < 10; ++i) {                                      \
            int job = i * 64 + lane;                                        \
            int jr = job / 10, jk = job - jr * 10;                          \
            p[(jk * 4 + 0) * KSTRIDE + jr] = st[i].x;                       \
            p[(jk * 4 + 1) * KSTRIDE + jr] = st[i].y;                       \
            p[(jk * 4 + 2) * KSTRIDE + jr] = st[i].z;                       \
            p[(jk * 4 + 3) * KSTRIDE + jr] = st[i].w;                       \
        }                                                                   \
    }

    float acc[HDIM];
#pragma unroll
    for (int j = 0; j < HDIM; ++j) acc[j] = 0.0f;

    STAGE_LOAD(0);
    STAGE_WRITE(0);

    for (int c = 0; c < NCHUNK; ++c) {
        int b = c & 1;
        if (c + 1 < NCHUNK) STAGE_LOAD(c + 1);
        const float* w0 = W1 + c * KB * HDIM;
        __syncthreads();
#pragma unroll 4
        for (int k = 0; k < KB; ++k) {
            float xv = xT[b][k * KSTRIDE + lane];
            const float* w = w0 + k * HDIM;
#pragma unroll
            for (int j = 0; j < HDIM; ++j) acc[j] = fmaf(xv, w[j], acc[j]);
        }
        __syncthreads();
        if (c + 1 < NCHUNK) STAGE_WRITE((c + 1) & 1);
    }

    long row = base + lane;
    if (row < n) {
        float4* o = (float4*)(t1 + row * HDIM);
        o[0] = make_float4(acc[0], acc[1], acc[2], acc[3]);
        o[1] = make_float4(acc[4], acc[5], acc[6], acc[7]);
        o[2] = make_float4(acc[8], acc[9], acc[10], acc[11]);
        o[3] = make_float4(acc[12], acc[13], acc[14], acc[15]);
    }
#undef STAGE_LOAD
#undef STAGE_WRITE
}

// ---- K1: gemm rows [0, ga*64) || count ----------------------------------
__global__ __launch_bounds__(64) void fused_a(const float* __restrict__ x,
                                              const float* __restrict__ W1,
                                              float* __restrict__ t1,
                                              const int* __restrict__ dst,
                                              int* __restrict__ cnt,
                                              int n, int e, int ga) {
    __shared__ float xT[2][KB * KSTRIDE];
    if ((int)blockIdx.x < ga) {
        gemm_body(x, W1, t1, xT, (long)blockIdx.x * 64, n);
    } else {
        int chunk = blockIdx.x - ga;
        int base = chunk * EPB + (int)threadIdx.x * 4;
#pragma unroll
        for (int r = 0; r < 4; ++r) {
            int i = base + r * 256;
            if (i + 3 < e) {
                int4 d = *(const int4*)(dst + i);
                atomicAdd(&cnt[d.x], 1);
                atomicAdd(&cnt[d.y], 1);
                atomicAdd(&cnt[d.z], 1);
                atomicAdd(&cnt[d.w], 1);
            } else {
                for (int k = i; k < e && k < i + 4; ++k) atomicAdd(&cnt[dst[k]], 1);
            }
        }
    }
}

// ---- K3: gemm rows [ga*64, N) || scatter --------------------------------
__global__ __launch_bounds__(64) void fused_b(const float* __restrict__ x,
                                              const float* __restrict__ W1,
                                              float* __restrict__ t1,
                                              const int* __restrict__ src,
                                              const int* __restrict__ dst,
                                              const int* __restrict__ rowptr,
                                              int* __restrict__ cursor,
                                              int* __restrict__ col,
                                              int n, int e, int ga, int gb) {
    __shared__ float xT[2][KB * KSTRIDE];
    if ((int)blockIdx.x < gb) {
        gemm_body(x, W1, t1, xT, (long)(ga + blockIdx.x) * 64, n);
    } else {
        int chunk = blockIdx.x - gb;
        int base = chunk * EPB + (int)threadIdx.x * 4;
#pragma unroll
        for (int r = 0; r < 4; ++r) {
            int i = base + r * 256;
            if (i + 3 < e) {
                int4 d = *(const int4*)(dst + i);
                int4 s = *(const int4*)(src + i);
                col[rowptr[d.x] + atomicAdd(&cursor[d.x], 1)] = s.x;
                col[rowptr[d.y] + atomicAdd(&cursor[d.y], 1)] = s.y;
                col[rowptr[d.z] + atomicAdd(&cursor[d.z], 1)] = s.z;
                col[rowptr[d.w] + atomicAdd(&cursor[d.w], 1)] = s.w;
            } else {
                for (int k = i; k < e && k < i + 4; ++k) {
                    int d = dst[k];
                    col[rowptr[d] + atomicAdd(&cursor[d], 1)] = src[k];
                }
            }
        }
    }
}

// exclusive scan of cnt -> rowptr, plus dinv = rsqrt(cnt+1) fused.
__global__ __launch_bounds__(1024) void scan_k(const int* __restrict__ cnt,
                                               int* __restrict__ rowptr,
                                               float* __restrict__ dinv, int n) {
    __shared__ int sdata[1024];
    int tid = threadIdx.x;
    int chunk = (n + 1023) >> 10;
    int s0 = tid * chunk;
    int s1 = s0 + chunk; if (s1 > n) s1 = n;
    int sum = 0;
    for (int i = s0; i < s1; ++i) {
        int c = cnt[i];
        dinv[i] = 1.0f / sqrtf((float)(c + 1));
        sum += c;
    }
    sdata[tid] = sum;
    __syncthreads();
    for (int off = 1; off < 1024; off <<= 1) {
        int v = sdata[tid];
        int u = (tid >= off) ? sdata[tid - off] : 0;
        __syncthreads();
        sdata[tid] = v + u;
        __syncthreads();
    }
    int run = sdata[tid] - sum;   // exclusive prefix
    for (int i = s0; i < s1; ++i) { rowptr[i] = run; run += cnt[i]; }
    if (tid == 0) rowptr[n] = sdata[1023];
}

// ---- aggregation 1 + relu + (h @ W2) fused ------------------------------
// 16 lanes per node (one per hidden dim). dinv[s] gathered per edge since
// t1 is unscaled.
__global__ __launch_bounds__(256) void agg1(const float* __restrict__ t1,
                                            const int* __restrict__ rowptr,
                                            const int* __restrict__ col,
                                            const float* __restrict__ dinv,
                                            const float* __restrict__ b1,
                                            const float* __restrict__ W2,
                                            float* __restrict__ t2s, int n) {
    int tid = blockIdx.x * 256 + threadIdx.x;
    int node = tid >> 4;
    int j = tid & 15;
    if (node >= n) return;
    float dn = dinv[node];
    float acc = t1[node * HDIM + j] * dn;          // self-loop term
    int e0 = rowptr[node], e1 = rowptr[node + 1];
    for (int e = e0; e < e1; ++e) {
        int s = col[e];
        acc += t1[s * HDIM + j] * dinv[s];
    }
    float h = acc * dn + b1[j];
    h = h > 0.0f ? h : 0.0f;
    // t2[c] = sum_j h_j * W2[j][c], 16-lane butterfly reduce
    float p0 = h * W2[j * 3 + 0];
    float p1 = h * W2[j * 3 + 1];
    float p2 = h * W2[j * 3 + 2];
#pragma unroll
    for (int off = 8; off > 0; off >>= 1) {
        p0 += __shfl_xor(p0, off, 16);
        p1 += __shfl_xor(p1, off, 16);
        p2 += __shfl_xor(p2, off, 16);
    }
    if (j == 0) {
        *(float4*)(t2s + node * 4) = make_float4(p0 * dn, p1 * dn, p2 * dn, 0.0f);
    }
}

// ---- aggregation 2 + bias + log_softmax ---------------------------------
__global__ __launch_bounds__(256) void agg2(const float* __restrict__ t2s,
                                            const int* __restrict__ rowptr,
                                            const int* __restrict__ col,
                                            const float* __restrict__ dinv,
                                            const float* __restrict__ b2,
                                            float* __restrict__ out, int n) {
    int node = blockIdx.x * 256 + threadIdx.x;
    if (node >= n) return;
    float4 a = *(const float4*)(t2s + node * 4);
    float a0 = a.x, a1 = a.y, a2 = a.z;
    int e0 = rowptr[node], e1 = rowptr[node + 1];
#pragma unroll 4
    for (int e = e0; e < e1; ++e) {
        int s = col[e];
        float4 v = *(const float4*)(t2s + s * 4);
        a0 += v.x; a1 += v.y; a2 += v.z;
    }
    float dn = dinv[node];
    float l0 = a0 * dn + b2[0];
    float l1 = a1 * dn + b2[1];
    float l2 = a2 * dn + b2[2];
    float m = fmaxf(l0, fmaxf(l1, l2));
    float lse = logf(expf(l0 - m) + expf(l1 - m) + expf(l2 - m)) + m;
    out[node * 3 + 0] = l0 - lse;
    out[node * 3 + 1] = l1 - lse;
    out[node * 3 + 2] = l2 - lse;
}

extern "C" void kernel_launch(void* const* d_in, const int* in_sizes, int n_in,
                              void* d_out, int out_size, void* d_ws, size_t ws_size,
                              hipStream_t stream) {
    const float* x  = (const float*)d_in[0];
    const int*   ei = (const int*)d_in[1];
    const float* W1 = (const float*)d_in[2];
    const float* b1 = (const float*)d_in[3];
    const float* W2 = (const float*)d_in[4];
    const float* b2 = (const float*)d_in[5];
    const int N = in_sizes[0] / FIN;
    const int E = in_sizes[1] / 2;
    const int* src = ei;
    const int* dst = ei + E;

    char* ws = (char*)d_ws;
    auto alloc = [&](size_t bytes) {
        char* p = ws;
        ws += (bytes + 255) & ~(size_t)255;
        return p;
    };
    size_t npad = ((size_t)N * 4 + 255) & ~(size_t)255;
    int*   cnt    = (int*)alloc(N * 4);
    int*   cursor = (int*)alloc(N * 4);     // adjacent to cnt: one zero_k covers both
    int*   rowptr = (int*)alloc((size_t)(N + 1) * 4);
    float* dinv   = (float*)alloc(N * 4);
    int*   col    = (int*)alloc((size_t)E * 4);
    float* t1     = (float*)alloc((size_t)N * HDIM * 4);
    float* t2s    = (float*)alloc((size_t)N * 4 * 4);

    int n4 = (int)(npad * 2 / 16);          // cnt+cursor region as int4s
    zero_k<<<(n4 + 255) / 256, 256, 0, stream>>>((int4*)cnt, n4);

    int gemm_blocks = (N + 63) / 64;        // 1563
    int ga = (gemm_blocks + 1) / 2;         // 782 rows-blocks in K1
    int gb = gemm_blocks - ga;              // 781 rows-blocks in K3
    int light = (E + EPB - 1) / EPB;        // 3125 count/scatter blocks

    fused_a<<<ga + light, 64, 0, stream>>>(x, W1, t1, dst, cnt, N, E, ga);
    scan_k<<<1, 1024, 0, stream>>>(cnt, rowptr, dinv, N);
    fused_b<<<gb + light, 64, 0, stream>>>(x, W1, t1, src, dst, rowptr, cursor, col,
                                           N, E, ga, gb);
    agg1<<<(N * 16 + 255) / 256, 256, 0, stream>>>(t1, rowptr, col, dinv, b1, W2, t2s, N);
    agg2<<<(N + 255) / 256, 256, 0, stream>>>(t2s, rowptr, col, dinv, b2, (float*)d_out, N);
}